// Round 4
// baseline (22.449 us; speedup 1.0000x reference)
//
#include <hip/hip_runtime.h>

#define S_LEN 4096
#define DIM   64
#define HALF  50
#define RB    128           // query rows per block
#define WQ    16            // query rows per wave (8 waves)
#define THREADS 512
#define KCAP  256           // staged keys: kstart=r0-64 aligned, span<=242 -> 8 tiles
#define SCALE 0.125f

typedef __attribute__((ext_vector_type(8))) short bf16x8;
typedef __attribute__((ext_vector_type(4))) float f32x4;

__device__ __forceinline__ unsigned int bf16_rne(float f) {
    unsigned int u = __float_as_uint(f);
    return (u + 0x7fffu + ((u >> 16) & 1u)) >> 16;
}
__device__ __forceinline__ unsigned int pk2(float lo, float hi) {
    return bf16_rne(lo) | (bf16_rne(hi) << 16);
}

// LDS: K  [256 keys][64 d] bf16, 128B rows, 16B slots, slot' = slot ^ (key&7)   (32KB)
//      V^T[64 d][256 keys] bf16, 512B rows, 16B slots, slot' = slot ^ (d&7)     (32KB)
//      P  [8 waves][16 q][40 k] bf16 per-wave scratch, wave-internal sync only  (10KB)
// total 74KB -> 2 blocks/CU: stage phase of one block overlaps compute of the other.
__global__ __launch_bounds__(THREADS)
void lattn_mfma(const float* __restrict__ Q, const float* __restrict__ K,
                const float* __restrict__ V, float* __restrict__ O) {
    __shared__ unsigned short Ks[KCAP * 64];
    __shared__ unsigned short Vs[DIM * KCAP];
    __shared__ unsigned short Ps[8 * 16 * 40];

    // bijective XCD swizzle: consecutive r0-blocks (overlapping halos) share an XCD L2
    const int nwg = gridDim.x;                 // 512
    const int cpx = nwg >> 3;
    const int bid = blockIdx.x;
    const int logical = (bid & 7) * cpx + (bid >> 3);
    const int bh = logical >> 5;               // 32 x-blocks per bh
    const int r0 = (logical & 31) * RB;

    const size_t base = (size_t)bh * (S_LEN * DIM);
    const float* Qg = Q + base;
    const float* Kg = K + base;
    const float* Vg = V + base;
    float*       Og = O + base;

    const int kstart = (r0 >= HALF) ? ((r0 - HALF) & ~31) : 0;
    const int kend   = min(S_LEN, r0 + RB + HALF);   // exclusive
    const int nstep  = (kend - kstart + 31) >> 5;    // <= 8
    const int nkeys  = nstep << 5;

    const int u = threadIdx.x;

    // ---- stage K -> bf16 LDS (row-major, slot-XOR) ----
    for (int idx = u; idx < (nkeys << 3); idx += THREADS) {
        const int krow = idx >> 3;
        const int oct  = idx & 7;
        const int kg   = kstart + krow;
        unsigned int w0, w1, w2, w3;
        if (kg < kend) {
            const float4 a = *(const float4*)(Kg + (size_t)kg * DIM + oct * 8);
            const float4 b = *(const float4*)(Kg + (size_t)kg * DIM + oct * 8 + 4);
            w0 = pk2(a.x, a.y); w1 = pk2(a.z, a.w);
            w2 = pk2(b.x, b.y); w3 = pk2(b.z, b.w);
        } else { w0 = w1 = w2 = w3 = 0u; }
        *(uint4*)(Ks + krow * 64 + ((oct ^ (krow & 7)) << 3)) = make_uint4(w0, w1, w2, w3);
    }

    // ---- stage V -> transposed bf16 LDS (pairs of keys per u32, slot-XOR) ----
    for (int idx = u; idx < (nkeys << 2); idx += THREADS) {
        const int kp = idx >> 3;                 // key-pair index
        const int m  = idx & 7;                  // d-octet owner (and rotation seed)
        const int d0 = m * 8;
        const int k0 = kp * 2;
        const int kg = kstart + k0;
        unsigned int pw[8];
        if (kg < kend) {                          // kend even -> pair never straddles
            const float* va = Vg + (size_t)kg * DIM + d0;
            const float* vb = va + DIM;
            float a0[8], a1[8];
            *(float4*)a0 = *(const float4*)va;  *(float4*)(a0 + 4) = *(const float4*)(va + 4);
            *(float4*)a1 = *(const float4*)vb;  *(float4*)(a1 + 4) = *(const float4*)(vb + 4);
            #pragma unroll
            for (int j = 0; j < 8; ++j) pw[j] = pk2(a0[j], a1[j]);
        } else {
            #pragma unroll
            for (int j = 0; j < 8; ++j) pw[j] = 0u;
        }
        // rotated write order: the 8 lanes sharing this key-pair hit 8 distinct banks
        #pragma unroll
        for (int j = 0; j < 8; ++j) {
            const int jj = (j + m) & 7;
            const int d  = d0 + jj;
            const int sl = (k0 >> 3) ^ (d & 7);
            *(unsigned int*)(Vs + d * KCAP + sl * 8 + (k0 & 7)) = pw[jj];
        }
    }

    // ---- Q^T B-fragments straight from global (scale folded) ----
    const int lane = u & 63;
    const int wv_  = u >> 6;
    const int g  = lane >> 4;
    const int cc = lane & 15;
    const int qlo = r0 + WQ * wv_;

    bf16x8 qf[2];
    #pragma unroll
    for (int ds = 0; ds < 2; ++ds) {
        const float* src = Qg + (size_t)(qlo + cc) * DIM + ds * 32 + g * 8;
        const float4 a = *(const float4*)src;
        const float4 b = *(const float4*)(src + 4);
        uint4 t = make_uint4(pk2(a.x * SCALE, a.y * SCALE), pk2(a.z * SCALE, a.w * SCALE),
                             pk2(b.x * SCALE, b.y * SCALE), pk2(b.z * SCALE, b.w * SCALE));
        qf[ds] = __builtin_bit_cast(bf16x8, t);
    }

    __syncthreads();

    f32x4 oacc[4] = {};
    float denom = 0.f;

    // per-wave step range (only tiles intersecting this wave's band)
    int lo = (qlo >= HALF) ? (qlo - HALF) : 0;
    lo = max(kstart, lo & ~31);
    const int t0 = (lo - kstart) >> 5;
    const int hi = min(kend, qlo + WQ - 1 + HALF + 1);
    const int t1 = (hi - kstart + 31) >> 5;

    unsigned short* Pw = Ps + wv_ * (16 * 40);

    for (int st = t0; st < t1; ++st) {
        const int kb = st << 5;   // local key base of this 32-key step

        // --- swapped QK^T: S^T[key][q] ---
        f32x4 sacc[2] = {};       // [kt]
        #pragma unroll
        for (int ds = 0; ds < 2; ++ds) {
            #pragma unroll
            for (int kt = 0; kt < 2; ++kt) {
                const int krow = kb + kt * 16 + cc;
                const int sl   = (ds * 4 + g) ^ (krow & 7);
                const bf16x8 ka = *(const bf16x8*)(Ks + krow * 64 + sl * 8);
                sacc[kt] = __builtin_amdgcn_mfma_f32_16x16x32_bf16(ka, qf[ds], sacc[kt], 0, 0, 0);
            }
        }

        // --- mask + exp + P write (per-wave LDS, no barrier) ---
        const int q = qlo + cc;
        #pragma unroll
        for (int kt = 0; kt < 2; ++kt) {
            float w4[4];
            const int keyb = kstart + kb + kt * 16 + g * 4;
            #pragma unroll
            for (int r = 0; r < 4; ++r) {
                const int key = keyb + r;
                const float e = __expf(sacc[kt][r]);
                const int dd  = key - q;
                const bool ok = (dd >= -HALF) && (dd <= HALF) && (key < S_LEN);
                w4[r] = ok ? e : 0.f;
                denom += w4[r];
            }
            *(uint2*)(Pw + cc * 40 + kt * 16 + g * 4) = make_uint2(pk2(w4[0], w4[1]), pk2(w4[2], w4[3]));
        }

        // --- PV: O^T += V^T x P^T ---
        const bf16x8 pf = *(const bf16x8*)(Pw + cc * 40 + g * 8);
        #pragma unroll
        for (int dt = 0; dt < 4; ++dt) {
            const int d  = dt * 16 + cc;
            const int sl = ((kb >> 3) + g) ^ (d & 7);
            const bf16x8 vf = *(const bf16x8*)(Vs + d * KCAP + sl * 8);
            oacc[dt] = __builtin_amdgcn_mfma_f32_16x16x32_bf16(vf, pf, oacc[dt], 0, 0, 0);
        }
    }

    // ---- normalize + store ----
    denom += __shfl_xor(denom, 16);
    denom += __shfl_xor(denom, 32);
    const float rinv = 1.f / denom;
    float* dst = Og + (size_t)(qlo + cc) * DIM;
    #pragma unroll
    for (int dt = 0; dt < 4; ++dt) {
        const f32x4 o = oacc[dt];
        *(float4*)(dst + dt * 16 + g * 4) =
            make_float4(o[0] * rinv, o[1] * rinv, o[2] * rinv, o[3] * rinv);
    }
}

extern "C" void kernel_launch(void* const* d_in, const int* in_sizes, int n_in,
                              void* d_out, int out_size, void* d_ws, size_t ws_size,
                              hipStream_t stream) {
    const float* q = (const float*)d_in[0];
    const float* k = (const float*)d_in[1];
    const float* v = (const float*)d_in[2];
    float* o = (float*)d_out;
    const int nbh = in_sizes[0] / (S_LEN * DIM);      // B*H = 16
    dim3 grid((S_LEN / RB) * nbh);                    // 512 blocks = 2/CU
    lattn_mfma<<<grid, THREADS, 0, stream>>>(q, k, v, o);
}